// Round 1
// baseline (13.159 us; speedup 1.0000x reference)
//
#include <hip/hip_runtime.h>

// OffsetSubtraction: for each (b,w,f), out = subed - sub[clip(w+delay)] where
// delay in order [0, 1..d, -1..-d] minimizes |subed - sub[...]| (first-min wins).
// B=8, W=4096, F=64, fp32.

#define B_DIM 8
#define W_DIM 4096
#define F_DIM 64
#define FVEC  (F_DIM / 4)   // 16 float4 per (b,w) row

__global__ __launch_bounds__(256) void offsub_kernel(
    const float4* __restrict__ subed,
    const float4* __restrict__ sub,
    const int* __restrict__ d_ptr,
    float4* __restrict__ out)
{
    const int tid = blockIdx.x * blockDim.x + threadIdx.x;
    const int total = B_DIM * W_DIM * FVEC;
    if (tid >= total) return;

    const int d = *d_ptr;  // wave-uniform scalar load

    const int fv = tid & (FVEC - 1);          // float4 index within row
    const int bw = tid / FVEC;
    const int w  = bw & (W_DIM - 1);
    const int b  = bw / W_DIM;

    const size_t rowBase = (size_t)b * W_DIM * FVEC + fv;

    const float4 s = subed[tid];

    // delay = 0
    float4 g = sub[rowBase + (size_t)w * FVEC];
    float rx = s.x - g.x, ry = s.y - g.y, rz = s.z - g.z, rw = s.w - g.w;
    float ax = fabsf(rx), ay = fabsf(ry), az = fabsf(rz), aw = fabsf(rw);
    float bx = rx, by = ry, bz = rz, bww = rw;

    // delays +1..+d, then -1..-d (matches jnp.argmin first-min tie order)
    for (int pass = 0; pass < 2; ++pass) {
        for (int dlt = 1; dlt <= d; ++dlt) {
            int wi = (pass == 0) ? min(w + dlt, W_DIM - 1) : max(w - dlt, 0);
            g = sub[rowBase + (size_t)wi * FVEC];
            float tx = s.x - g.x, ty = s.y - g.y, tz = s.z - g.z, tw = s.w - g.w;
            float cx = fabsf(tx), cy = fabsf(ty), cz = fabsf(tz), cw = fabsf(tw);
            if (cx < ax) { ax = cx; bx = tx; }
            if (cy < ay) { ay = cy; by = ty; }
            if (cz < az) { az = cz; bz = tz; }
            if (cw < aw) { aw = cw; bww = tw; }
        }
    }

    float4 o; o.x = bx; o.y = by; o.z = bz; o.w = bww;
    out[tid] = o;
}

extern "C" void kernel_launch(void* const* d_in, const int* in_sizes, int n_in,
                              void* d_out, int out_size, void* d_ws, size_t ws_size,
                              hipStream_t stream)
{
    const float4* subed = (const float4*)d_in[0];
    const float4* sub   = (const float4*)d_in[1];
    const int*    dptr  = (const int*)d_in[2];
    float4* out = (float4*)d_out;

    const int total  = B_DIM * W_DIM * FVEC;   // 524288 threads
    const int block  = 256;
    const int grid   = (total + block - 1) / block;  // 2048 blocks

    offsub_kernel<<<grid, block, 0, stream>>>(subed, sub, dptr, out);
}

// Round 2
// 10.854 us; speedup vs baseline: 1.2123x; 1.2123x over previous
//
#include <hip/hip_runtime.h>

// OffsetSubtraction: out[b,w,f] = subed[b,w,f] - sub[b,clip(w+delay),f], where
// delay in ORDER [0, +1..+d, -1..-d] minimizes |residual| (first-min wins,
// matching jnp.argmin). B=8, W=4096, F=64, fp32, d=8 (specialized; generic
// fallback for other d).

#define B_DIM 8
#define W_DIM 4096
#define FVEC  16          // 64 floats = 16 float4 per (b,w) row
#define RW    2           // w-positions per thread (windows overlap 17/18 rows)
#define WP    (W_DIM / RW)   // 2048 w-pairs
#define LOG2_WP 11

__device__ __forceinline__ float4 f4sub(float4 a, float4 b) {
    float4 r; r.x = a.x - b.x; r.y = a.y - b.y; r.z = a.z - b.z; r.w = a.w - b.w;
    return r;
}

// best = (|cand| < |best|) ? cand : best   (abs folds into v_cmp modifiers)
__device__ __forceinline__ void upd(float4& best, float4 cand) {
    best.x = (fabsf(cand.x) < fabsf(best.x)) ? cand.x : best.x;
    best.y = (fabsf(cand.y) < fabsf(best.y)) ? cand.y : best.y;
    best.z = (fabsf(cand.z) < fabsf(best.z)) ? cand.z : best.z;
    best.w = (fabsf(cand.w) < fabsf(best.w)) ? cand.w : best.w;
}

__global__ __launch_bounds__(256) void offsub_kernel(
    const float4* __restrict__ subed,
    const float4* __restrict__ sub,
    const int* __restrict__ d_ptr,
    float4* __restrict__ out)
{
    const int tid = blockIdx.x * blockDim.x + threadIdx.x;
    const int d = *d_ptr;                 // wave-uniform

    const int fv   = tid & (FVEC - 1);
    const int rest = tid >> 4;
    const int p    = rest & (WP - 1);
    const int b    = rest >> LOG2_WP;
    const int w0   = p * RW;

    const size_t base = (size_t)b * (W_DIM * FVEC) + fv;

    if (__builtin_expect(d == 8, 1)) {
        // Union window: rows w0-8 .. w0+RW-1+8  => 18 rows, clipped.
        float4 g[16 + RW];
        #pragma unroll
        for (int k = 0; k < 16 + RW; ++k) {
            int wi = w0 - 8 + k;
            wi = wi < 0 ? 0 : (wi > W_DIM - 1 ? W_DIM - 1 : wi);
            g[k] = sub[base + (size_t)wi * FVEC];
        }
        #pragma unroll
        for (int r = 0; r < RW; ++r) {
            const int w = w0 + r;
            const float4 s = subed[base + (size_t)w * FVEC];
            float4 best = f4sub(s, g[r + 8]);          // delay 0
            #pragma unroll
            for (int dd = 1; dd <= 8; ++dd)            // +1..+8
                upd(best, f4sub(s, g[r + 8 + dd]));
            #pragma unroll
            for (int dd = 1; dd <= 8; ++dd)            // -1..-8
                upd(best, f4sub(s, g[r + 8 - dd]));
            out[base + (size_t)w * FVEC] = best;
        }
    } else {
        // Generic-d fallback (runtime loop, same tie order).
        for (int r = 0; r < RW; ++r) {
            const int w = w0 + r;
            const float4 s = subed[base + (size_t)w * FVEC];
            float4 best = f4sub(s, sub[base + (size_t)w * FVEC]);
            for (int pass = 0; pass < 2; ++pass) {
                for (int dd = 1; dd <= d; ++dd) {
                    int wi = (pass == 0) ? min(w + dd, W_DIM - 1)
                                         : max(w - dd, 0);
                    upd(best, f4sub(s, sub[base + (size_t)wi * FVEC]));
                }
            }
            out[base + (size_t)w * FVEC] = best;
        }
    }
}

extern "C" void kernel_launch(void* const* d_in, const int* in_sizes, int n_in,
                              void* d_out, int out_size, void* d_ws, size_t ws_size,
                              hipStream_t stream)
{
    const float4* subed = (const float4*)d_in[0];
    const float4* sub   = (const float4*)d_in[1];
    const int*    dptr  = (const int*)d_in[2];
    float4* out = (float4*)d_out;

    const int total = B_DIM * WP * FVEC;   // 262144 threads
    const int block = 256;
    const int grid  = (total + block - 1) / block;   // 1024 blocks

    offsub_kernel<<<grid, block, 0, stream>>>(subed, sub, dptr, out);
}